// Round 1
// baseline (886.779 us; speedup 1.0000x reference)
//
#include <hip/hip_runtime.h>
#include <math.h>

#define NDOM 6
#define BB 4
#define TT 1024
#define DD 768
#define PP 3
#define HH 2
#define DHH 32
#define II 64
#define SS (PP*TT)       // 3072
#define LNEPS 1e-5f

// ---------------------------------------------------------------------------
// Kernel 1: Q projection. Q[n,b,t,i] = sum_d x[n,b,t,d] * Wq[n,d,i]
// block = 256 (4 waves), each wave owns 8 rows; x staged in LDS in 256-float
// chunks (wave-private region, no barriers needed).
// ---------------------------------------------------------------------------
__global__ __launch_bounds__(256) void q_proj_kernel(
    const float* __restrict__ x, const float* __restrict__ Wq,
    float* __restrict__ Q)
{
  __shared__ float xs[4][8][256];
  const int wave = threadIdx.x >> 6;
  const int lane = threadIdx.x & 63;
  const int row0 = blockIdx.x * 32 + wave * 8;       // global row (n*B+b)*T + t
  const int n = row0 / (BB * TT);
  const float* wq = Wq + (size_t)n * DD * II;
  float acc[8];
#pragma unroll
  for (int r = 0; r < 8; ++r) acc[r] = 0.f;

  for (int cc = 0; cc < 3; ++cc) {
    // load chunk: 8 rows x 256 floats; each lane: 8 float4
#pragma unroll
    for (int k = 0; k < 8; ++k) {
      float4 v = *(const float4*)(x + (size_t)(row0 + k) * DD + cc * 256 + lane * 4);
      *(float4*)(&xs[wave][k][lane * 4]) = v;
    }
    for (int d = 0; d < 256; d += 4) {
      float w0 = wq[(size_t)(cc * 256 + d + 0) * II + lane];
      float w1 = wq[(size_t)(cc * 256 + d + 1) * II + lane];
      float w2 = wq[(size_t)(cc * 256 + d + 2) * II + lane];
      float w3 = wq[(size_t)(cc * 256 + d + 3) * II + lane];
#pragma unroll
      for (int r = 0; r < 8; ++r) {
        float4 xv = *(const float4*)(&xs[wave][r][d]);
        acc[r] = fmaf(xv.x, w0, acc[r]);
        acc[r] = fmaf(xv.y, w1, acc[r]);
        acc[r] = fmaf(xv.z, w2, acc[r]);
        acc[r] = fmaf(xv.w, w3, acc[r]);
      }
    }
  }
#pragma unroll
  for (int r = 0; r < 8; ++r)
    Q[(size_t)(row0 + r) * II + lane] = acc[r];
}

// ---------------------------------------------------------------------------
// Kernel 2: K/V projection of concatenated history.
// prior[n,b,p*T+t,:] = hist[p,n,b,t,:].  K = prior@Wk, V = prior@Wv.
// block = 256: waves (0,1)=K,V of rows 0-7; waves (2,3)=K,V of rows 8-15.
// ---------------------------------------------------------------------------
__global__ __launch_bounds__(256) void kv_proj_kernel(
    const float* __restrict__ hist, const float* __restrict__ Wk,
    const float* __restrict__ Wv, float* __restrict__ K, float* __restrict__ V)
{
  __shared__ float xs[16][256];
  const int tid = threadIdx.x;
  const int wave = tid >> 6;
  const int lane = tid & 63;
  const int grp = wave >> 1;     // row group (0/1)
  const int iskv = wave & 1;     // 0 = K, 1 = V
  const int brow0 = blockIdx.x * 16;                 // global row (n*B+b)*S + s
  const int n = brow0 / (BB * SS);
  const int b = (brow0 / SS) % BB;
  const int s0 = brow0 % SS;
  const int p = s0 / TT;
  const int t0 = s0 % TT;       // 16 rows stay inside one p (16 | 1024)
  const float* src = hist + (((size_t)(p * NDOM + n) * BB + b) * TT + t0) * DD;
  const float* W = iskv ? Wv : Wk;
  float* Out = iskv ? V : K;
  float acc[8];
#pragma unroll
  for (int r = 0; r < 8; ++r) acc[r] = 0.f;

  for (int cc = 0; cc < 3; ++cc) {
    __syncthreads();
    // cooperative load: 16 rows x 256 floats = 1024 float4 by 256 threads
#pragma unroll
    for (int u = 0; u < 4; ++u) {
      int idx = tid + 256 * u;
      int r = idx >> 6;
      int d4 = idx & 63;
      float4 v = *(const float4*)(src + (size_t)r * DD + cc * 256 + d4 * 4);
      *(float4*)(&xs[r][d4 * 4]) = v;
    }
    __syncthreads();
    const float* wb = W + (size_t)(cc * 256) * II + lane;
    for (int d = 0; d < 256; d += 4) {
      float w0 = wb[(size_t)(d + 0) * II];
      float w1 = wb[(size_t)(d + 1) * II];
      float w2 = wb[(size_t)(d + 2) * II];
      float w3 = wb[(size_t)(d + 3) * II];
#pragma unroll
      for (int r = 0; r < 8; ++r) {
        float4 xv = *(const float4*)(&xs[grp * 8 + r][d]);
        acc[r] = fmaf(xv.x, w0, acc[r]);
        acc[r] = fmaf(xv.y, w1, acc[r]);
        acc[r] = fmaf(xv.z, w2, acc[r]);
        acc[r] = fmaf(xv.w, w3, acc[r]);
      }
    }
  }
#pragma unroll
  for (int r = 0; r < 8; ++r)
    Out[(size_t)(brow0 + grp * 8 + r) * II + lane] = acc[r];
}

// ---------------------------------------------------------------------------
// Kernel 3: flash attention.  block = 256, one block per (n,b,h, 64-row tile).
// thread (r = tid>>2, c = tid&3): row r, key quarter c (16 keys / thread).
// K/V tiles in LDS with XOR swizzle on 8-float granule keyed by (j>>4)&3 = c
// so QK/PV reads hit 4 distinct banks. Scores/probs in registers; softmax
// reductions via 4-lane shfl_xor.
// ---------------------------------------------------------------------------
__global__ __launch_bounds__(256) void attn_kernel(
    const float* __restrict__ Q, const float* __restrict__ Kt,
    const float* __restrict__ Vt, const int* __restrict__ mask,
    float* __restrict__ O)
{
  __shared__ float ks[64 * 32];
  __shared__ float vs[64 * 32];
  const int tid = threadIdx.x;
  const int r = tid >> 2;
  const int c = tid & 3;
  int blk = blockIdx.x;
  const int ttile = blk & 15;  blk >>= 4;
  const int h = blk & 1;       blk >>= 1;
  const int b = blk & 3;       blk >>= 2;
  const int n = blk;
  const int qrow0 = (n * BB + b) * TT + ttile * 64;
  const int krow0 = (n * BB + b) * SS;

  float4 q4[8];
  {
    const float* qp = Q + (size_t)(qrow0 + r) * II + h * DHH;
#pragma unroll
    for (int i = 0; i < 8; ++i) q4[i] = *(const float4*)(qp + i * 4);
  }

  float m = -1e30f, l = 0.f;
  float acc[32];
#pragma unroll
  for (int i = 0; i < 32; ++i) acc[i] = 0.f;
  const float scale = 0.17677669529663687f;   // 1/sqrt(32)

  for (int kt = 0; kt < SS / 64; ++kt) {
    __syncthreads();
    {
      const float* kb = Kt + ((size_t)(krow0 + kt * 64)) * II + h * DHH;
      const float* vb = Vt + ((size_t)(krow0 + kt * 64)) * II + h * DHH;
#pragma unroll
      for (int u = 0; u < 2; ++u) {
        int idx = tid + 256 * u;          // 0..511
        int j = idx >> 3;                 // key row 0..63
        int d4 = (idx & 7) * 4;           // 0,4,...,28
        int sw = ((((d4 >> 3) ^ ((j >> 4) & 3)) << 3) | (d4 & 7));
        float4 kk = *(const float4*)(kb + (size_t)j * II + d4);
        *(float4*)(&ks[j * 32 + sw]) = kk;
        float4 vv = *(const float4*)(vb + (size_t)j * II + d4);
        *(float4*)(&vs[j * 32 + sw]) = vv;
      }
    }
    // mask bias for my 16 keys
    float mb[16];
    {
      int sbase = kt * 64 + c * 16;
#pragma unroll
      for (int jj = 0; jj < 16; ++jj) {
        int sg = sbase + jj;
        mb[jj] = (1.0f - (float)mask[b * TT + (sg & (TT - 1))]) * -10000.0f;
      }
    }
    __syncthreads();

    // QK^T
    float p[16];
#pragma unroll
    for (int jj = 0; jj < 16; ++jj) {
      int j = c * 16 + jj;
      float s = 0.f;
#pragma unroll
      for (int g = 0; g < 8; ++g) {
        int off = ((((g >> 1) ^ c) << 3) | ((g * 4) & 7));
        float4 kk = *(const float4*)(&ks[j * 32 + off]);
        s = fmaf(q4[g].x, kk.x, s);
        s = fmaf(q4[g].y, kk.y, s);
        s = fmaf(q4[g].z, kk.z, s);
        s = fmaf(q4[g].w, kk.w, s);
      }
      p[jj] = fmaf(s, scale, mb[jj]);
    }
    // online softmax
    float tm = p[0];
#pragma unroll
    for (int jj = 1; jj < 16; ++jj) tm = fmaxf(tm, p[jj]);
    tm = fmaxf(tm, __shfl_xor(tm, 1));
    tm = fmaxf(tm, __shfl_xor(tm, 2));
    float newm = fmaxf(m, tm);
    float f = __expf(m - newm);
    float ts = 0.f;
#pragma unroll
    for (int jj = 0; jj < 16; ++jj) { p[jj] = __expf(p[jj] - newm); ts += p[jj]; }
    ts += __shfl_xor(ts, 1);
    ts += __shfl_xor(ts, 2);
    l = l * f + ts;
    m = newm;
#pragma unroll
    for (int i = 0; i < 32; ++i) acc[i] *= f;
    // PV over my 16 keys, all 32 dims
#pragma unroll
    for (int jj = 0; jj < 16; ++jj) {
      int j = c * 16 + jj;
      float pj = p[jj];
#pragma unroll
      for (int g = 0; g < 8; ++g) {
        int off = ((((g >> 1) ^ c) << 3) | ((g * 4) & 7));
        float4 vv = *(const float4*)(&vs[j * 32 + off]);
        acc[g * 4 + 0] = fmaf(pj, vv.x, acc[g * 4 + 0]);
        acc[g * 4 + 1] = fmaf(pj, vv.y, acc[g * 4 + 1]);
        acc[g * 4 + 2] = fmaf(pj, vv.z, acc[g * 4 + 2]);
        acc[g * 4 + 3] = fmaf(pj, vv.w, acc[g * 4 + 3]);
      }
    }
  }
  // combine the 4 key-quarter partials per row
#pragma unroll
  for (int i = 0; i < 32; ++i) {
    acc[i] += __shfl_xor(acc[i], 1);
    acc[i] += __shfl_xor(acc[i], 2);
  }
  float inv = 1.0f / l;
  float* op = O + (size_t)(qrow0 + r) * II + h * DHH;
#pragma unroll
  for (int i = 0; i < 8; ++i) {
    int d = c * 8 + i;
    op[d] = acc[d] * inv;
  }
}

// ---------------------------------------------------------------------------
// Kernel 4: out-projection + residual + LayerNorm.  block = 256, 4 rows/block.
// thread owns 3 output dims (tid, tid+256, tid+512) for each of 4 rows.
// ---------------------------------------------------------------------------
__global__ __launch_bounds__(256) void oproj_ln_kernel(
    const float* __restrict__ x, const float* __restrict__ O,
    const float* __restrict__ Wo, const float* __restrict__ gamma,
    const float* __restrict__ beta, float* __restrict__ out)
{
  __shared__ float os[4][II];
  __shared__ float red[2][4][4];
  const int tid = threadIdx.x;
  const int row0 = blockIdx.x * 4;
  const int n = row0 / (BB * TT);

  os[tid >> 6][tid & 63] = O[(size_t)(row0 + (tid >> 6)) * II + (tid & 63)];
  __syncthreads();

  const float* wo = Wo + (size_t)n * II * DD;
  float acc[4][3];
#pragma unroll
  for (int r = 0; r < 4; ++r)
#pragma unroll
    for (int dc = 0; dc < 3; ++dc)
      acc[r][dc] = x[(size_t)(row0 + r) * DD + tid + dc * 256];

  for (int i = 0; i < II; ++i) {
    float w0 = wo[(size_t)i * DD + tid];
    float w1 = wo[(size_t)i * DD + tid + 256];
    float w2 = wo[(size_t)i * DD + tid + 512];
#pragma unroll
    for (int r = 0; r < 4; ++r) {
      float ov = os[r][i];
      acc[r][0] = fmaf(ov, w0, acc[r][0]);
      acc[r][1] = fmaf(ov, w1, acc[r][1]);
      acc[r][2] = fmaf(ov, w2, acc[r][2]);
    }
  }

  // LayerNorm stats per row
#pragma unroll
  for (int r = 0; r < 4; ++r) {
    float s1 = acc[r][0] + acc[r][1] + acc[r][2];
    float s2 = acc[r][0] * acc[r][0] + acc[r][1] * acc[r][1] + acc[r][2] * acc[r][2];
#pragma unroll
    for (int off = 1; off < 64; off <<= 1) {
      s1 += __shfl_xor(s1, off);
      s2 += __shfl_xor(s2, off);
    }
    if ((tid & 63) == 0) { red[0][r][tid >> 6] = s1; red[1][r][tid >> 6] = s2; }
  }
  __syncthreads();

  float g0 = gamma[(size_t)n * DD + tid];
  float g1 = gamma[(size_t)n * DD + tid + 256];
  float g2 = gamma[(size_t)n * DD + tid + 512];
  float b0 = beta[(size_t)n * DD + tid];
  float b1 = beta[(size_t)n * DD + tid + 256];
  float b2 = beta[(size_t)n * DD + tid + 512];

#pragma unroll
  for (int r = 0; r < 4; ++r) {
    float s1 = red[0][r][0] + red[0][r][1] + red[0][r][2] + red[0][r][3];
    float s2 = red[1][r][0] + red[1][r][1] + red[1][r][2] + red[1][r][3];
    float mu = s1 * (1.0f / (float)DD);
    float var = s2 * (1.0f / (float)DD) - mu * mu;
    float rs = rsqrtf(var + LNEPS);
    float* po = out + (size_t)(row0 + r) * DD;
    po[tid]       = (acc[r][0] - mu) * rs * g0 + b0;
    po[tid + 256] = (acc[r][1] - mu) * rs * g1 + b1;
    po[tid + 512] = (acc[r][2] - mu) * rs * g2 + b2;
  }
}

// ---------------------------------------------------------------------------
extern "C" void kernel_launch(void* const* d_in, const int* in_sizes, int n_in,
                              void* d_out, int out_size, void* d_ws, size_t ws_size,
                              hipStream_t stream) {
  const float* x     = (const float*)d_in[0];
  const float* hist  = (const float*)d_in[1];
  const int*   mask  = (const int*)d_in[2];
  const float* Wq    = (const float*)d_in[3];
  const float* Wk    = (const float*)d_in[4];
  const float* Wv    = (const float*)d_in[5];
  const float* Wo    = (const float*)d_in[6];
  const float* gamma = (const float*)d_in[7];
  const float* beta  = (const float*)d_in[8];
  float* out = (float*)d_out;

  float* ws = (float*)d_ws;
  float* Q = ws;                                   // N*B*T*I
  float* K = Q + (size_t)NDOM * BB * TT * II;      // N*B*S*I
  float* V = K + (size_t)NDOM * BB * SS * II;      // N*B*S*I
  float* O = V + (size_t)NDOM * BB * SS * II;      // N*B*T*I

  q_proj_kernel<<<NDOM * BB * TT / 32, 256, 0, stream>>>(x, Wq, Q);
  kv_proj_kernel<<<NDOM * BB * SS / 16, 256, 0, stream>>>(hist, Wk, Wv, K, V);
  attn_kernel<<<NDOM * BB * HH * (TT / 64), 256, 0, stream>>>(Q, K, V, mask, O);
  oproj_ln_kernel<<<NDOM * BB * TT / 4, 256, 0, stream>>>(x, O, Wo, gamma, beta, out);
}

// Round 3
// 297.363 us; speedup vs baseline: 2.9821x; 2.9821x over previous
//
#include <hip/hip_runtime.h>
#include <hip/hip_bf16.h>
#include <math.h>

#define NDOM 6
#define BB 4
#define TT 1024
#define DD 768
#define PP 3
#define HH 2
#define DHH 32
#define II 64
#define SS (PP*TT)       // 3072
#define LNEPS 1e-5f

typedef unsigned int uint;
typedef uint  u32x4  __attribute__((ext_vector_type(4)));
typedef float f32x4  __attribute__((ext_vector_type(4)));
typedef float f32x16 __attribute__((ext_vector_type(16)));
typedef __bf16 bf16x8 __attribute__((ext_vector_type(8)));

// D = A(32x16) * B(16x32) + C.  A row = lane&31, k = (lane>>5)*8+j.
// B col = lane&31, k = (lane>>5)*8+j.  D: col = lane&31, row=(r&3)+8*(r>>2)+4*(lane>>5).
__device__ __forceinline__ f32x16 mfma32(u32x4 a, u32x4 b, f32x16 c) {
  return __builtin_amdgcn_mfma_f32_32x32x16_bf16(
      __builtin_bit_cast(bf16x8, a), __builtin_bit_cast(bf16x8, b), c, 0, 0, 0);
}

__device__ __forceinline__ uint pkbf(float a, float b) {
  union { __bf16 h[2]; uint u; } v;
  v.h[0] = (__bf16)a; v.h[1] = (__bf16)b;
  return v.u;
}

// ---------------------------------------------------------------------------
// Prep: bf16 transposed weights + exp2-domain mask bias.
// Bkv[c][k]: c<64 -> Wk col c ; c>=64 -> Wv col c-64.   [128][768] bf16
// Bq[n][c][k]                                            [6][64][768] bf16
// bias2[b][s] = (1-mask[b][s%T]) * (-10000) * log2(e)    [4][3072] f32
// ---------------------------------------------------------------------------
__global__ __launch_bounds__(256) void prep_kernel(
    const int* __restrict__ mask, const float* __restrict__ Wk,
    const float* __restrict__ Wv, const float* __restrict__ Wq,
    __hip_bfloat16* __restrict__ Bkv, __hip_bfloat16* __restrict__ Bq,
    float* __restrict__ bias2)
{
  int i = blockIdx.x * 256 + threadIdx.x;
  const int N1 = 128 * 768;          // Bkv
  const int N2 = NDOM * 64 * 768;    // Bq
  if (i < N1) {
    int c = i / 768, k = i % 768;
    float v = (c < 64) ? Wk[k * 64 + c] : Wv[k * 64 + (c - 64)];
    Bkv[i] = __float2bfloat16(v);
  } else if (i < N1 + N2) {
    int j = i - N1;
    int n = j / (64 * 768);
    int rem = j % (64 * 768);
    int c = rem / 768, k = rem % 768;
    Bq[j] = __float2bfloat16(Wq[((size_t)n * 768 + k) * 64 + c]);
  } else if (i < N1 + N2 + BB * SS) {
    int j = i - N1 - N2;
    int b = j / SS, s = j % SS;
    bias2[j] = (1.0f - (float)mask[b * TT + (s & (TT - 1))]) * (-14426.950408889634f);
  }
}

// ---------------------------------------------------------------------------
// Q GEMM: Q[row][64] bf16 = x[row][768] @ Wq[n].  BM=128, BN=64, BK=64.
// 4 waves: wr=w>>1 (row half), wc=w&1 (col half of 32).
// A staged f32->bf16 into XOR-swizzled LDS; B frags direct from global Bq.
// ---------------------------------------------------------------------------
__global__ __launch_bounds__(256) void q_gemm_kernel(
    const float* __restrict__ x, const __hip_bfloat16* __restrict__ Bq,
    __hip_bfloat16* __restrict__ Qo)
{
  __shared__ uint As[128 * 32];      // [row][32 u32] = 64 bf16 per row
  const int tid = threadIdx.x;
  const int lane = tid & 63, w = tid >> 6;
  const int wr = w >> 1, wc = w & 1;
  const int cl = lane & 31, hi = lane >> 5;
  const int brow = blockIdx.x * 128;
  const int n = brow >> 12;                     // / (B*T) = 4096
  const float* Asrc = x + (size_t)brow * 768;
  const __hip_bfloat16* Bn = Bq + (size_t)n * 64 * 768;

  f32x16 acc0 = {}, acc1 = {};
  const int r0 = tid >> 3, oct = tid & 7;

  for (int kk = 0; kk < 12; ++kk) {
    __syncthreads();
#pragma unroll
    for (int g = 0; g < 4; ++g) {
      const float* ap = Asrc + (size_t)(r0 + 32 * g) * 768 + kk * 64 + oct * 8;
      float4 f0 = *(const float4*)ap;
      float4 f1 = *(const float4*)(ap + 4);
      int row = r0 + 32 * g;
      u32x4 pk = {pkbf(f0.x, f0.y), pkbf(f0.z, f0.w), pkbf(f1.x, f1.y), pkbf(f1.z, f1.w)};
      *(u32x4*)&As[row * 32 + ((oct ^ (row & 7)) << 2)] = pk;
    }
    __syncthreads();
#pragma unroll
    for (int ks = 0; ks < 4; ++ks) {
      int kg = kk * 64 + ks * 16 + hi * 8;
      u32x4 b = *(const u32x4*)(Bn + (size_t)(wc * 32 + cl) * 768 + kg);
      int ro0 = wr * 64 + cl;
      int ro1 = ro0 + 32;
      int oc = ks * 2 + hi;
      u32x4 a0 = *(const u32x4*)&As[ro0 * 32 + ((oc ^ (ro0 & 7)) << 2)];
      u32x4 a1 = *(const u32x4*)&As[ro1 * 32 + ((oc ^ (ro1 & 7)) << 2)];
      acc0 = mfma32(a0, b, acc0);
      acc1 = mfma32(a1, b, acc1);
    }
  }
  // store: D col = cl (out col), row = crow(r,hi)
  int c = wc * 32 + cl;
#pragma unroll
  for (int r = 0; r < 16; ++r) {
    int rl = (r & 3) + 8 * (r >> 2) + 4 * hi;
    Qo[(size_t)(brow + wr * 64 + rl) * 64 + c] = __float2bfloat16(acc0[r]);
    Qo[(size_t)(brow + wr * 64 + 32 + rl) * 64 + c] = __float2bfloat16(acc1[r]);
  }
}

// ---------------------------------------------------------------------------
// KV GEMM: rows = concat history (s = p*T+t), BM=128, BN=128 (cols 0-63 K,
// 64-127 V), BK=64.  K written row-major [s][64]; V written transposed
// Vt[nb][c][3072] for attention's PV A-operand.
// ---------------------------------------------------------------------------
__global__ __launch_bounds__(256) void kv_gemm_kernel(
    const float* __restrict__ hist, const __hip_bfloat16* __restrict__ Bkv,
    __hip_bfloat16* __restrict__ Kb, __hip_bfloat16* __restrict__ Vtb)
{
  __shared__ uint As[128 * 32];
  const int tid = threadIdx.x;
  const int lane = tid & 63, w = tid >> 6;
  const int wr = w >> 1, wc = w & 1;
  const int cl = lane & 31, hi = lane >> 5;
  const int brow = blockIdx.x * 128;
  const int nb = brow / SS;
  const int n = nb >> 2, b = nb & 3;
  const int s0 = brow % SS;
  const int p = s0 / TT, t0 = s0 % TT;         // 128 | 1024 so block stays in one p
  const float* Asrc = hist + (((size_t)(p * NDOM + n) * BB + b) * TT + t0) * 768;

  f32x16 acc00 = {}, acc01 = {}, acc10 = {}, acc11 = {};
  const int r0 = tid >> 3, oct = tid & 7;

  for (int kk = 0; kk < 12; ++kk) {
    __syncthreads();
#pragma unroll
    for (int g = 0; g < 4; ++g) {
      const float* ap = Asrc + (size_t)(r0 + 32 * g) * 768 + kk * 64 + oct * 8;
      float4 f0 = *(const float4*)ap;
      float4 f1 = *(const float4*)(ap + 4);
      int row = r0 + 32 * g;
      u32x4 pk = {pkbf(f0.x, f0.y), pkbf(f0.z, f0.w), pkbf(f1.x, f1.y), pkbf(f1.z, f1.w)};
      *(u32x4*)&As[row * 32 + ((oct ^ (row & 7)) << 2)] = pk;
    }
    __syncthreads();
#pragma unroll
    for (int ks = 0; ks < 4; ++ks) {
      int kg = kk * 64 + ks * 16 + hi * 8;
      u32x4 b0 = *(const u32x4*)(Bkv + (size_t)(wc * 64 + cl) * 768 + kg);
      u32x4 b1 = *(const u32x4*)(Bkv + (size_t)(wc * 64 + 32 + cl) * 768 + kg);
      int ro0 = wr * 64 + cl;
      int ro1 = ro0 + 32;
      int oc = ks * 2 + hi;
      u32x4 a0 = *(const u32x4*)&As[ro0 * 32 + ((oc ^ (ro0 & 7)) << 2)];
      u32x4 a1 = *(const u32x4*)&As[ro1 * 32 + ((oc ^ (ro1 & 7)) << 2)];
      acc00 = mfma32(a0, b0, acc00);
      acc01 = mfma32(a0, b1, acc01);
      acc10 = mfma32(a1, b0, acc10);
      acc11 = mfma32(a1, b1, acc11);
    }
  }

  if (wc == 0) {   // K half: cols 0..63
#pragma unroll
    for (int r = 0; r < 16; ++r) {
      int rl = (r & 3) + 8 * (r >> 2) + 4 * hi;
      size_t rbase0 = (size_t)(brow + wr * 64 + rl) * 64;
      size_t rbase1 = (size_t)(brow + wr * 64 + 32 + rl) * 64;
      Kb[rbase0 + cl]      = __float2bfloat16(acc00[r]);
      Kb[rbase0 + 32 + cl] = __float2bfloat16(acc01[r]);
      Kb[rbase1 + cl]      = __float2bfloat16(acc10[r]);
      Kb[rbase1 + 32 + cl] = __float2bfloat16(acc11[r]);
    }
  } else {         // V half: cols 64..127 -> Vt[c][s], packed 4 bf16 per group
#pragma unroll
    for (int k = 0; k < 4; ++k) {
      int sl0 = s0 + wr * 64 + 8 * k + 4 * hi;          // within-nb s of group start
      __hip_bfloat16* v0 = Vtb + ((size_t)nb * 64 + cl) * SS + sl0;
      __hip_bfloat16* v1 = Vtb + ((size_t)nb * 64 + 32 + cl) * SS + sl0;
      *(uint2*)v0        = uint2{pkbf(acc00[4*k], acc00[4*k+1]), pkbf(acc00[4*k+2], acc00[4*k+3])};
      *(uint2*)v1        = uint2{pkbf(acc01[4*k], acc01[4*k+1]), pkbf(acc01[4*k+2], acc01[4*k+3])};
      *(uint2*)(v0 + 32) = uint2{pkbf(acc10[4*k], acc10[4*k+1]), pkbf(acc10[4*k+2], acc10[4*k+3])};
      *(uint2*)(v1 + 32) = uint2{pkbf(acc11[4*k], acc11[4*k+1]), pkbf(acc11[4*k+2], acc11[4*k+3])};
    }
  }
}

// ---------------------------------------------------------------------------
// Flash attention, 1 wave = 32 queries of one (n,b,h).  No LDS.
// Swapped QK^T: P[s][q] = mfma(A=K tile, B=Q^T) -> col=q lane-local.
// O^T[d][q] accum via mfma(A=Vt slab, B=P).  Online softmax in exp2 domain.
// bid = g + 48*tile keeps a (n,b,h) group on one XCD (48 % 8 == 0).
// ---------------------------------------------------------------------------
struct AttnTile { u32x4 ka0, ka1, va0, va1; f32x4 b0, b1, b2, b3; };

__global__ __launch_bounds__(64) void attn_kernel(
    const __hip_bfloat16* __restrict__ Q, const __hip_bfloat16* __restrict__ K,
    const __hip_bfloat16* __restrict__ Vt, const float* __restrict__ bias2,
    float* __restrict__ O)
{
  const int lane = threadIdx.x;
  const int cl = lane & 31, hi = lane >> 5;
  const int bid = blockIdx.x;
  const int g = bid % 48;            // (n,b,h) group -> fixed XCD
  const int tile = bid / 48;         // 0..31
  const int h = g & 1, nb = g >> 1;
  const int b = nb & 3;
  const int qrow = nb * TT + tile * 32;

  const __hip_bfloat16* Qp = Q + (size_t)(qrow + cl) * 64 + h * 32 + hi * 8;
  u32x4 qf0 = *(const u32x4*)Qp;
  u32x4 qf1 = *(const u32x4*)(Qp + 16);

  const __hip_bfloat16* Kp = K + ((size_t)nb * SS + cl) * 64 + h * 32 + hi * 8;
  const __hip_bfloat16* Vp = Vt + ((size_t)nb * 64 + h * 32 + cl) * SS + hi * 8;
  const float* Bp = bias2 + b * SS + hi * 4;

  const float scale2 = 0.17677669529663687f * 1.4426950408889634f;

  f32x16 ot = {};
  float m = -1e30f, lsum = 0.f;

  auto loadTile = [&](int s0) {
    AttnTile t;
    t.ka0 = *(const u32x4*)(Kp + (size_t)s0 * 64);
    t.ka1 = *(const u32x4*)(Kp + (size_t)s0 * 64 + 16);
    t.va0 = *(const u32x4*)(Vp + s0);
    t.va1 = *(const u32x4*)(Vp + s0 + 16);
    t.b0 = *(const f32x4*)(Bp + s0);
    t.b1 = *(const f32x4*)(Bp + s0 + 8);
    t.b2 = *(const f32x4*)(Bp + s0 + 16);
    t.b3 = *(const f32x4*)(Bp + s0 + 24);
    return t;
  };

  auto compute = [&](const AttnTile& t) {
    f32x16 pz = {};
    pz = mfma32(t.ka0, qf0, pz);
    pz = mfma32(t.ka1, qf1, pz);
    float p[16];
#pragma unroll
    for (int r = 0; r < 16; ++r) {
      float bb = (r < 4) ? t.b0[r & 3] : (r < 8) ? t.b1[r & 3]
               : (r < 12) ? t.b2[r & 3] : t.b3[r & 3];
      p[r] = fmaf(pz[r], scale2, bb);
    }
    float tm = fmaxf(fmaxf(fmaxf(p[0], p[1]), fmaxf(p[2], p[3])),
                     fmaxf(fmaxf(p[4], p[5]), fmaxf(p[6], p[7])));
    tm = fmaxf(tm, fmaxf(fmaxf(fmaxf(p[8], p[9]), fmaxf(p[10], p[11])),
                         fmaxf(fmaxf(p[12], p[13]), fmaxf(p[14], p[15]))));
    tm = fmaxf(tm, __shfl_xor(tm, 32));
    float mn = fmaxf(m, tm);
    float f = exp2f(m - mn);
    float ts = 0.f;
#pragma unroll
    for (int r = 0; r < 16; ++r) { p[r] = exp2f(p[r] - mn); ts += p[r]; }
    ts += __shfl_xor(ts, 32);
    lsum = lsum * f + ts;
    m = mn;
#pragma unroll
    for (int i = 0; i < 16; ++i) ot[i] *= f;
    // P -> bf16 B-frags.  key(r) = (r&3)+8*(r>>2)+4*hi.
    uint pk01 = pkbf(p[0], p[1]),  pk23 = pkbf(p[2], p[3]);
    uint pk45 = pkbf(p[4], p[5]),  pk67 = pkbf(p[6], p[7]);
    uint pk89 = pkbf(p[8], p[9]),  pkAB = pkbf(p[10], p[11]);
    uint pkCD = pkbf(p[12], p[13]), pkEF = pkbf(p[14], p[15]);
    uint sw01 = __shfl_xor(pk01, 32), sw23 = __shfl_xor(pk23, 32);
    uint sw45 = __shfl_xor(pk45, 32), sw67 = __shfl_xor(pk67, 32);
    uint sw89 = __shfl_xor(pk89, 32), swAB = __shfl_xor(pkAB, 32);
    uint swCD = __shfl_xor(pkCD, 32), swEF = __shfl_xor(pkEF, 32);
    bool h1 = (hi != 0);
    u32x4 pf0 = {h1 ? sw45 : pk01, h1 ? sw67 : pk23,
                 h1 ? pk45 : sw01, h1 ? pk67 : sw23};
    u32x4 pf1 = {h1 ? swCD : pk89, h1 ? swEF : pkAB,
                 h1 ? pkCD : sw89, h1 ? pkEF : swAB};
    ot = mfma32(t.va0, pf0, ot);
    ot = mfma32(t.va1, pf1, ot);
  };

  AttnTile tA = loadTile(0);
  for (int kt = 0; kt < 96; kt += 2) {
    AttnTile tB = loadTile((kt + 1) * 32);
    compute(tA);
    int kn = (kt + 2 < 96) ? kt + 2 : 95;
    tA = loadTile(kn * 32);
    compute(tB);
  }

  float inv = 1.0f / lsum;
  float* op = O + (size_t)(qrow + cl) * 64 + h * 32;
#pragma unroll
  for (int k = 0; k < 4; ++k) {
    float4 v = {ot[4*k] * inv, ot[4*k+1] * inv, ot[4*k+2] * inv, ot[4*k+3] * inv};
    *(float4*)(op + 8 * k + 4 * hi) = v;
  }
}

// ---------------------------------------------------------------------------
// Kernel 4: out-projection + residual + LayerNorm (unchanged, f32).
// ---------------------------------------------------------------------------
__global__ __launch_bounds__(256) void oproj_ln_kernel(
    const float* __restrict__ x, const float* __restrict__ O,
    const float* __restrict__ Wo, const float* __restrict__ gamma,
    const float* __restrict__ beta, float* __restrict__ out)
{
  __shared__ float os[4][II];
  __shared__ float red[2][4][4];
  const int tid = threadIdx.x;
  const int row0 = blockIdx.x * 4;
  const int n = row0 / (BB * TT);

  os[tid >> 6][tid & 63] = O[(size_t)(row0 + (tid >> 6)) * II + (tid & 63)];
  __syncthreads();

  const float* wo = Wo + (size_t)n * II * DD;
  float acc[4][3];
#pragma unroll
  for (int r = 0; r < 4; ++r)
#pragma unroll
    for (int dc = 0; dc < 3; ++dc)
      acc[r][dc] = x[(size_t)(row0 + r) * DD + tid + dc * 256];

  for (int i = 0; i < II; ++i) {
    float w0 = wo[(size_t)i * DD + tid];
    float w1 = wo[(size_t)i * DD + tid + 256];
    float w2 = wo[(size_t)i * DD + tid + 512];
#pragma unroll
    for (int r = 0; r < 4; ++r) {
      float ov = os[r][i];
      acc[r][0] = fmaf(ov, w0, acc[r][0]);
      acc[r][1] = fmaf(ov, w1, acc[r][1]);
      acc[r][2] = fmaf(ov, w2, acc[r][2]);
    }
  }

#pragma unroll
  for (int r = 0; r < 4; ++r) {
    float s1 = acc[r][0] + acc[r][1] + acc[r][2];
    float s2 = acc[r][0] * acc[r][0] + acc[r][1] * acc[r][1] + acc[r][2] * acc[r][2];
#pragma unroll
    for (int off = 1; off < 64; off <<= 1) {
      s1 += __shfl_xor(s1, off);
      s2 += __shfl_xor(s2, off);
    }
    if ((tid & 63) == 0) { red[0][r][tid >> 6] = s1; red[1][r][tid >> 6] = s2; }
  }
  __syncthreads();

  float g0 = gamma[(size_t)n * DD + tid];
  float g1 = gamma[(size_t)n * DD + tid + 256];
  float g2 = gamma[(size_t)n * DD + tid + 512];
  float b0 = beta[(size_t)n * DD + tid];
  float b1 = beta[(size_t)n * DD + tid + 256];
  float b2 = beta[(size_t)n * DD + tid + 512];

#pragma unroll
  for (int r = 0; r < 4; ++r) {
    float s1 = red[0][r][0] + red[0][r][1] + red[0][r][2] + red[0][r][3];
    float s2 = red[1][r][0] + red[1][r][1] + red[1][r][2] + red[1][r][3];
    float mu = s1 * (1.0f / (float)DD);
    float var = s2 * (1.0f / (float)DD) - mu * mu;
    float rs = rsqrtf(var + LNEPS);
    float* po = out + (size_t)(row0 + r) * DD;
    po[tid]       = (acc[r][0] - mu) * rs * g0 + b0;
    po[tid + 256] = (acc[r][1] - mu) * rs * g1 + b1;
    po[tid + 512] = (acc[r][2] - mu) * rs * g2 + b2;
  }
}

// ---------------------------------------------------------------------------
extern "C" void kernel_launch(void* const* d_in, const int* in_sizes, int n_in,
                              void* d_out, int out_size, void* d_ws, size_t ws_size,
                              hipStream_t stream) {
  const float* x     = (const float*)d_in[0];
  const float* hist  = (const float*)d_in[1];
  const int*   mask  = (const int*)d_in[2];
  const float* Wq    = (const float*)d_in[3];
  const float* Wk    = (const float*)d_in[4];
  const float* Wv    = (const float*)d_in[5];
  const float* Wo    = (const float*)d_in[6];
  const float* gamma = (const float*)d_in[7];
  const float* beta  = (const float*)d_in[8];
  float* out = (float*)d_out;

  char* ws = (char*)d_ws;
  __hip_bfloat16* Qb  = (__hip_bfloat16*)ws;                    ws += (size_t)NDOM*BB*TT*II*2;   // 3.15 MB
  __hip_bfloat16* Kb  = (__hip_bfloat16*)ws;                    ws += (size_t)NDOM*BB*SS*II*2;   // 9.4 MB
  __hip_bfloat16* Vtb = (__hip_bfloat16*)ws;                    ws += (size_t)NDOM*BB*II*SS*2;   // 9.4 MB
  float*          Ob  = (float*)ws;                             ws += (size_t)NDOM*BB*TT*II*4;   // 6.3 MB
  __hip_bfloat16* Bkv = (__hip_bfloat16*)ws;                    ws += (size_t)128*768*2;
  __hip_bfloat16* Bq  = (__hip_bfloat16*)ws;                    ws += (size_t)NDOM*64*768*2;
  float*          bias2 = (float*)ws;                           ws += (size_t)BB*SS*4;

  prep_kernel<<<1584, 256, 0, stream>>>(mask, Wk, Wv, Wq, Bkv, Bq, bias2);
  q_gemm_kernel<<<NDOM * BB * TT / 128, 256, 0, stream>>>(x, Bq, Qb);
  kv_gemm_kernel<<<NDOM * BB * SS / 128, 256, 0, stream>>>(hist, Bkv, Kb, Vtb);
  attn_kernel<<<48 * (TT / 32), 64, 0, stream>>>(Qb, Kb, Vtb, bias2, Ob);
  oproj_ln_kernel<<<NDOM * BB * TT / 4, 256, 0, stream>>>(x, Ob, Wo, gamma, beta, out);
}

// Round 4
// 262.593 us; speedup vs baseline: 3.3770x; 1.1324x over previous
//
#include <hip/hip_runtime.h>
#include <hip/hip_bf16.h>
#include <math.h>

#define NDOM 6
#define BB 4
#define TT 1024
#define DD 768
#define PP 3
#define HH 2
#define DHH 32
#define II 64
#define SS (PP*TT)       // 3072
#define NROW (NDOM*BB*TT) // 24576
#define NSPLIT 3
#define LNEPS 1e-5f

typedef unsigned int uint;
typedef unsigned short ushort;
typedef uint  u32x4  __attribute__((ext_vector_type(4)));
typedef int   i32x2  __attribute__((ext_vector_type(2)));
typedef float f32x4  __attribute__((ext_vector_type(4)));
typedef float f32x16 __attribute__((ext_vector_type(16)));
typedef __bf16 bf16x8 __attribute__((ext_vector_type(8)));

// D = A(32x16) * B(16x32) + C.  A row = lane&31, k = (lane>>5)*8+j.
// B col = lane&31, k = (lane>>5)*8+j.  D: col = lane&31, row=(r&3)+8*(r>>2)+4*(lane>>5).
__device__ __forceinline__ f32x16 mfma32(u32x4 a, u32x4 b, f32x16 c) {
  return __builtin_amdgcn_mfma_f32_32x32x16_bf16(
      __builtin_bit_cast(bf16x8, a), __builtin_bit_cast(bf16x8, b), c, 0, 0, 0);
}

__device__ __forceinline__ uint pkbf(float a, float b) {
  union { __bf16 h[2]; uint u; } v;
  v.h[0] = (__bf16)a; v.h[1] = (__bf16)b;
  return v.u;
}
__device__ __forceinline__ float b2f(uint u16) {
  union { uint i; float f; } v; v.i = u16 << 16; return v.f;
}

// x gets {a_lo | partner's b}, y gets {partner's a | b}  (32-lane halves)
__device__ __forceinline__ void plswap(uint a, uint b, uint& x, uint& y) {
#if __has_builtin(__builtin_amdgcn_permlane32_swap)
  i32x2 r = __builtin_amdgcn_permlane32_swap((int)a, (int)b, false, false);
  x = (uint)r.x; y = (uint)r.y;
#else
  uint sa = __shfl_xor(a, 32), sb = __shfl_xor(b, 32);
  bool h1 = (threadIdx.x & 32) != 0;
  x = h1 ? sb : a;
  y = h1 ? b : sa;
#endif
}

// ---------------------------------------------------------------------------
// Prep: bf16 transposed weights + exp2-domain mask bias.
// Bkv[c][k]: c<64 -> Wk col c ; c>=64 -> Wv col c-64.   [128][768] bf16
// Bq[n][c][k]                                            [6][64][768] bf16
// Bo[n][d][i] = Wo[n][i][d]                              [6][768][64] bf16
// bias2[b][s] = (1-mask[b][s%T]) * (-10000) * log2(e)    [4][3072] f32
// ---------------------------------------------------------------------------
__global__ __launch_bounds__(256) void prep_kernel(
    const int* __restrict__ mask, const float* __restrict__ Wk,
    const float* __restrict__ Wv, const float* __restrict__ Wq,
    const float* __restrict__ Wo,
    __hip_bfloat16* __restrict__ Bkv, __hip_bfloat16* __restrict__ Bq,
    __hip_bfloat16* __restrict__ Bo, float* __restrict__ bias2)
{
  int i = blockIdx.x * 256 + threadIdx.x;
  const int N1 = 128 * 768;          // Bkv
  const int N2 = NDOM * 64 * 768;    // Bq
  const int N3 = NDOM * 768 * 64;    // Bo
  if (i < N1) {
    int c = i / 768, k = i % 768;
    float v = (c < 64) ? Wk[k * 64 + c] : Wv[k * 64 + (c - 64)];
    Bkv[i] = __float2bfloat16(v);
  } else if (i < N1 + N2) {
    int j = i - N1;
    int n = j / (64 * 768);
    int rem = j % (64 * 768);
    int c = rem / 768, k = rem % 768;
    Bq[j] = __float2bfloat16(Wq[((size_t)n * 768 + k) * 64 + c]);
  } else if (i < N1 + N2 + N3) {
    int j = i - N1 - N2;
    int n = j / (768 * 64);
    int rem = j % (768 * 64);
    int d = rem / 64, k = rem % 64;
    Bo[j] = __float2bfloat16(Wo[((size_t)n * 64 + k) * 768 + d]);
  } else if (i < N1 + N2 + N3 + BB * SS) {
    int j = i - N1 - N2 - N3;
    int b = j / SS, s = j % SS;
    bias2[j] = (1.0f - (float)mask[b * TT + (s & (TT - 1))]) * (-14426.950408889634f);
  }
}

// ---------------------------------------------------------------------------
// Q GEMM: Q[row][64] bf16 = x[row][768] @ Wq[n].  BM=128, BN=64, BK=64.
// ---------------------------------------------------------------------------
__global__ __launch_bounds__(256) void q_gemm_kernel(
    const float* __restrict__ x, const __hip_bfloat16* __restrict__ Bq,
    __hip_bfloat16* __restrict__ Qo)
{
  __shared__ uint As[128 * 32];      // [row][32 u32] = 64 bf16 per row
  const int tid = threadIdx.x;
  const int lane = tid & 63, w = tid >> 6;
  const int wr = w >> 1, wc = w & 1;
  const int cl = lane & 31, hi = lane >> 5;
  const int brow = blockIdx.x * 128;
  const int n = brow >> 12;                     // / (B*T) = 4096
  const float* Asrc = x + (size_t)brow * 768;
  const __hip_bfloat16* Bn = Bq + (size_t)n * 64 * 768;

  f32x16 acc0 = {}, acc1 = {};
  const int r0 = tid >> 3, oct = tid & 7;

  for (int kk = 0; kk < 12; ++kk) {
    __syncthreads();
#pragma unroll
    for (int g = 0; g < 4; ++g) {
      const float* ap = Asrc + (size_t)(r0 + 32 * g) * 768 + kk * 64 + oct * 8;
      float4 f0 = *(const float4*)ap;
      float4 f1 = *(const float4*)(ap + 4);
      int row = r0 + 32 * g;
      u32x4 pk = {pkbf(f0.x, f0.y), pkbf(f0.z, f0.w), pkbf(f1.x, f1.y), pkbf(f1.z, f1.w)};
      *(u32x4*)&As[row * 32 + ((oct ^ (row & 7)) << 2)] = pk;
    }
    __syncthreads();
#pragma unroll
    for (int ks = 0; ks < 4; ++ks) {
      int kg = kk * 64 + ks * 16 + hi * 8;
      u32x4 b = *(const u32x4*)(Bn + (size_t)(wc * 32 + cl) * 768 + kg);
      int ro0 = wr * 64 + cl;
      int ro1 = ro0 + 32;
      int oc = ks * 2 + hi;
      u32x4 a0 = *(const u32x4*)&As[ro0 * 32 + ((oc ^ (ro0 & 7)) << 2)];
      u32x4 a1 = *(const u32x4*)&As[ro1 * 32 + ((oc ^ (ro1 & 7)) << 2)];
      acc0 = mfma32(a0, b, acc0);
      acc1 = mfma32(a1, b, acc1);
    }
  }
  int c = wc * 32 + cl;
#pragma unroll
  for (int r = 0; r < 16; ++r) {
    int rl = (r & 3) + 8 * (r >> 2) + 4 * hi;
    Qo[(size_t)(brow + wr * 64 + rl) * 64 + c] = __float2bfloat16(acc0[r]);
    Qo[(size_t)(brow + wr * 64 + 32 + rl) * 64 + c] = __float2bfloat16(acc1[r]);
  }
}

// ---------------------------------------------------------------------------
// KV GEMM: rows = concat history, BM=128, BN=128 (cols 0-63 K, 64-127 V).
// K row-major [s][64]; V transposed Vt[nb][c][3072].
// ---------------------------------------------------------------------------
__global__ __launch_bounds__(256) void kv_gemm_kernel(
    const float* __restrict__ hist, const __hip_bfloat16* __restrict__ Bkv,
    __hip_bfloat16* __restrict__ Kb, __hip_bfloat16* __restrict__ Vtb)
{
  __shared__ uint As[128 * 32];
  const int tid = threadIdx.x;
  const int lane = tid & 63, w = tid >> 6;
  const int wr = w >> 1, wc = w & 1;
  const int cl = lane & 31, hi = lane >> 5;
  const int brow = blockIdx.x * 128;
  const int nb = brow / SS;
  const int n = nb >> 2, b = nb & 3;
  const int s0 = brow % SS;
  const int p = s0 / TT, t0 = s0 % TT;
  const float* Asrc = hist + (((size_t)(p * NDOM + n) * BB + b) * TT + t0) * 768;

  f32x16 acc00 = {}, acc01 = {}, acc10 = {}, acc11 = {};
  const int r0 = tid >> 3, oct = tid & 7;

  for (int kk = 0; kk < 12; ++kk) {
    __syncthreads();
#pragma unroll
    for (int g = 0; g < 4; ++g) {
      const float* ap = Asrc + (size_t)(r0 + 32 * g) * 768 + kk * 64 + oct * 8;
      float4 f0 = *(const float4*)ap;
      float4 f1 = *(const float4*)(ap + 4);
      int row = r0 + 32 * g;
      u32x4 pk = {pkbf(f0.x, f0.y), pkbf(f0.z, f0.w), pkbf(f1.x, f1.y), pkbf(f1.z, f1.w)};
      *(u32x4*)&As[row * 32 + ((oct ^ (row & 7)) << 2)] = pk;
    }
    __syncthreads();
#pragma unroll
    for (int ks = 0; ks < 4; ++ks) {
      int kg = kk * 64 + ks * 16 + hi * 8;
      u32x4 b0 = *(const u32x4*)(Bkv + (size_t)(wc * 64 + cl) * 768 + kg);
      u32x4 b1 = *(const u32x4*)(Bkv + (size_t)(wc * 64 + 32 + cl) * 768 + kg);
      int ro0 = wr * 64 + cl;
      int ro1 = ro0 + 32;
      int oc = ks * 2 + hi;
      u32x4 a0 = *(const u32x4*)&As[ro0 * 32 + ((oc ^ (ro0 & 7)) << 2)];
      u32x4 a1 = *(const u32x4*)&As[ro1 * 32 + ((oc ^ (ro1 & 7)) << 2)];
      acc00 = mfma32(a0, b0, acc00);
      acc01 = mfma32(a0, b1, acc01);
      acc10 = mfma32(a1, b0, acc10);
      acc11 = mfma32(a1, b1, acc11);
    }
  }

  if (wc == 0) {   // K half
#pragma unroll
    for (int r = 0; r < 16; ++r) {
      int rl = (r & 3) + 8 * (r >> 2) + 4 * hi;
      size_t rbase0 = (size_t)(brow + wr * 64 + rl) * 64;
      size_t rbase1 = (size_t)(brow + wr * 64 + 32 + rl) * 64;
      Kb[rbase0 + cl]      = __float2bfloat16(acc00[r]);
      Kb[rbase0 + 32 + cl] = __float2bfloat16(acc01[r]);
      Kb[rbase1 + cl]      = __float2bfloat16(acc10[r]);
      Kb[rbase1 + 32 + cl] = __float2bfloat16(acc11[r]);
    }
  } else {         // V half -> Vt
#pragma unroll
    for (int k = 0; k < 4; ++k) {
      int sl0 = s0 + wr * 64 + 8 * k + 4 * hi;
      __hip_bfloat16* v0 = Vtb + ((size_t)nb * 64 + cl) * SS + sl0;
      __hip_bfloat16* v1 = Vtb + ((size_t)nb * 64 + 32 + cl) * SS + sl0;
      *(uint2*)v0        = uint2{pkbf(acc00[4*k], acc00[4*k+1]), pkbf(acc00[4*k+2], acc00[4*k+3])};
      *(uint2*)v1        = uint2{pkbf(acc01[4*k], acc01[4*k+1]), pkbf(acc01[4*k+2], acc01[4*k+3])};
      *(uint2*)(v0 + 32) = uint2{pkbf(acc10[4*k], acc10[4*k+1]), pkbf(acc10[4*k+2], acc10[4*k+3])};
      *(uint2*)(v1 + 32) = uint2{pkbf(acc11[4*k], acc11[4*k+1]), pkbf(acc11[4*k+2], acc11[4*k+3])};
    }
  }
}

// ---------------------------------------------------------------------------
// Flash attention, split-S by 3.  1 wave = 32 queries, 1024 keys, 64 keys/iter.
// Swapped QK^T (P col=q lane-local); O^T accum; exp2-domain online softmax
// with defer-max (THR=8); permlane32_swap P repack.  Unnormalized bf16
// partials + per-row (m,l) to workspace.
// ---------------------------------------------------------------------------
struct KV { u32x4 k0, k1, k2, k3, v0, v1, v2, v3; };

__global__ __launch_bounds__(64) void attn_kernel(
    const __hip_bfloat16* __restrict__ Q, const __hip_bfloat16* __restrict__ K,
    const __hip_bfloat16* __restrict__ Vt, const float* __restrict__ bias2,
    __hip_bfloat16* __restrict__ Op, float* __restrict__ Mp, float* __restrict__ Lp)
{
  const int lane = threadIdx.x;
  const int cl = lane & 31, hi = lane >> 5;
  const int bid = blockIdx.x;
  const int g = bid % 48;            // (n,b,h) group -> fixed XCD
  const int rest = bid / 48;         // 0..95
  const int sp = rest >> 5;          // split 0..2
  const int tile = rest & 31;        // q tile 0..31
  const int h = g & 1, nb = g >> 1;
  const int b = nb & 3;
  const int qrow = nb * TT + tile * 32;
  const int sbase = sp * (SS / NSPLIT);   // 1024 keys per split

  const __hip_bfloat16* Qp = Q + (size_t)(qrow + cl) * 64 + h * 32 + hi * 8;
  u32x4 qf0 = *(const u32x4*)Qp;
  u32x4 qf1 = *(const u32x4*)(Qp + 16);

  const __hip_bfloat16* Kp = K + ((size_t)nb * SS + sbase + cl) * 64 + h * 32 + hi * 8;
  const __hip_bfloat16* Vp = Vt + ((size_t)nb * 64 + h * 32 + cl) * SS + sbase + hi * 8;
  const float* Bp = bias2 + b * SS + sbase + hi * 4;

  const float scale2 = 0.17677669529663687f * 1.4426950408889634f;

  f32x16 ot = {};
  float m = -1e30f, lsum = 0.f;

  auto loadKV = [&](int it) {
    KV t;
    const __hip_bfloat16* kp = Kp + (size_t)it * 64 * 64;
    t.k0 = *(const u32x4*)kp;
    t.k1 = *(const u32x4*)(kp + 16);
    t.k2 = *(const u32x4*)(kp + 32 * 64);
    t.k3 = *(const u32x4*)(kp + 32 * 64 + 16);
    const __hip_bfloat16* vp = Vp + it * 64;
    t.v0 = *(const u32x4*)vp;
    t.v1 = *(const u32x4*)(vp + 16);
    t.v2 = *(const u32x4*)(vp + 32);
    t.v3 = *(const u32x4*)(vp + 48);
    return t;
  };

  auto compute = [&](const KV& t, int it) {
    f32x16 pz0 = {}, pz1 = {};
    pz0 = mfma32(t.k0, qf0, pz0);
    pz0 = mfma32(t.k1, qf1, pz0);
    pz1 = mfma32(t.k2, qf0, pz1);
    pz1 = mfma32(t.k3, qf1, pz1);
    const float* bp = Bp + it * 64;
    f32x4 b4[8];
#pragma unroll
    for (int q = 0; q < 8; ++q) b4[q] = *(const f32x4*)(bp + 8 * q);
    float p[32];
#pragma unroll
    for (int r = 0; r < 16; ++r) {
      p[r]      = fmaf(pz0[r], scale2, b4[r >> 2][r & 3]);
      p[16 + r] = fmaf(pz1[r], scale2, b4[4 + (r >> 2)][r & 3]);
    }
    float tm = p[0];
#pragma unroll
    for (int r = 1; r < 32; ++r) tm = fmaxf(tm, p[r]);
    tm = fmaxf(tm, __shfl_xor(tm, 32));
    if (!__all(tm - m <= 8.f)) {       // defer-max: skip rescale when bounded
      float mn = fmaxf(m, tm);
      float f = exp2f(m - mn);
#pragma unroll
      for (int i = 0; i < 16; ++i) ot[i] *= f;
      lsum *= f;
      m = mn;
    }
    float ts = 0.f;
#pragma unroll
    for (int r = 0; r < 32; ++r) { p[r] = exp2f(p[r] - m); ts += p[r]; }
    ts += __shfl_xor(ts, 32);
    lsum += ts;
    // P -> bf16 B-frags via permlane32_swap
    u32x4 pf0, pf1, pf2, pf3;
    {
      uint x0, y0, x1, y1;
      plswap(pkbf(p[0], p[1]),  pkbf(p[4], p[5]),  x0, y0);
      plswap(pkbf(p[2], p[3]),  pkbf(p[6], p[7]),  x1, y1);
      pf0 = u32x4{x0, x1, y0, y1};
      plswap(pkbf(p[8], p[9]),  pkbf(p[12], p[13]), x0, y0);
      plswap(pkbf(p[10], p[11]), pkbf(p[14], p[15]), x1, y1);
      pf1 = u32x4{x0, x1, y0, y1};
      plswap(pkbf(p[16], p[17]), pkbf(p[20], p[21]), x0, y0);
      plswap(pkbf(p[18], p[19]), pkbf(p[22], p[23]), x1, y1);
      pf2 = u32x4{x0, x1, y0, y1};
      plswap(pkbf(p[24], p[25]), pkbf(p[28], p[29]), x0, y0);
      plswap(pkbf(p[26], p[27]), pkbf(p[30], p[31]), x1, y1);
      pf3 = u32x4{x0, x1, y0, y1};
    }
    ot = mfma32(t.v0, pf0, ot);
    ot = mfma32(t.v1, pf1, ot);
    ot = mfma32(t.v2, pf2, ot);
    ot = mfma32(t.v3, pf3, ot);
  };

  KV cur = loadKV(0);
#pragma unroll 1
  for (int it = 0; it < 16; ++it) {
    KV nxt = loadKV(it + 1 < 16 ? it + 1 : 15);
    compute(cur, it);
    cur = nxt;
  }

  // store unnormalized O^T partial (bf16) + m/l
  __hip_bfloat16* op = Op + ((size_t)sp * NROW + qrow + cl) * 64 + h * 32 + 4 * hi;
#pragma unroll
  for (int k = 0; k < 4; ++k) {
    uint2 wv = {pkbf(ot[4*k], ot[4*k+1]), pkbf(ot[4*k+2], ot[4*k+3])};
    *(uint2*)(op + 8 * k) = wv;
  }
  if (lane < 32) {
    int mi = ((sp * 24 + nb) * 2 + h) * TT + tile * 32 + cl;
    Mp[mi] = m;
    Lp[mi] = lsum;
  }
}

// ---------------------------------------------------------------------------
// Combine the 3 split partials -> Ob bf16 [row][64].
// ---------------------------------------------------------------------------
__global__ __launch_bounds__(256) void combine_kernel(
    const __hip_bfloat16* __restrict__ Op, const float* __restrict__ Mp,
    const float* __restrict__ Lp, __hip_bfloat16* __restrict__ Ob)
{
  const int idx = blockIdx.x * 256 + threadIdx.x;   // 49152
  const int h = idx & 1, gr = idx >> 1;             // gr: global row
  const int nb = gr >> 10, trow = gr & 1023;
  const int MLS = 24 * 2 * TT;                      // per-split m/l stride
  const int mi = (nb * 2 + h) * TT + trow;
  float m0 = Mp[mi], m1 = Mp[mi + MLS], m2 = Mp[mi + 2 * MLS];
  float l0 = Lp[mi], l1 = Lp[mi + MLS], l2 = Lp[mi + 2 * MLS];
  float ms = fmaxf(m0, fmaxf(m1, m2));
  float w0 = exp2f(m0 - ms), w1 = exp2f(m1 - ms), w2 = exp2f(m2 - ms);
  float inv = 1.0f / (l0 * w0 + l1 * w1 + l2 * w2);
  w0 *= inv; w1 *= inv; w2 *= inv;

  const size_t SPO = (size_t)NROW * 64;
  const __hip_bfloat16* p0 = Op + (size_t)gr * 64 + h * 32;
  __hip_bfloat16* ob = Ob + (size_t)gr * 64 + h * 32;
#pragma unroll
  for (int j = 0; j < 4; ++j) {
    u32x4 a = *(const u32x4*)(p0 + j * 8);
    u32x4 b = *(const u32x4*)(p0 + SPO + j * 8);
    u32x4 c = *(const u32x4*)(p0 + 2 * SPO + j * 8);
    uint o[4];
#pragma unroll
    for (int e = 0; e < 4; ++e) {
      float lo = b2f(a[e] & 0xffffu) * w0 + b2f(b[e] & 0xffffu) * w1 + b2f(c[e] & 0xffffu) * w2;
      float hi2 = b2f(a[e] >> 16) * w0 + b2f(b[e] >> 16) * w1 + b2f(c[e] >> 16) * w2;
      o[e] = pkbf(lo, hi2);
    }
    *(u32x4*)(ob + j * 8) = u32x4{o[0], o[1], o[2], o[3]};
  }
}

// ---------------------------------------------------------------------------
// Out-projection (MFMA) + residual + LayerNorm.  Block 256 = 4 waves,
// 32 rows/block; wave w owns cols [w*192, +192) = 6 col-tiles of 32.
// LN stats in-register (shfl over 32 lanes) + LDS cross-wave reduce.
// ---------------------------------------------------------------------------
__global__ __launch_bounds__(256) void oproj_ln_kernel(
    const float* __restrict__ x, const __hip_bfloat16* __restrict__ Ob,
    const __hip_bfloat16* __restrict__ Bo, const float* __restrict__ gamma,
    const float* __restrict__ beta, float* __restrict__ out)
{
  __shared__ float red[4][32][2];
  __shared__ float redf[32][2];
  const int tid = threadIdx.x;
  const int lane = tid & 63, w = tid >> 6;
  const int cl = lane & 31, hi = lane >> 5;
  const int row0 = blockIdx.x * 32;
  const int n = row0 >> 12;

  const __hip_bfloat16* Ap = Ob + (size_t)(row0 + cl) * 64 + hi * 8;
  const __hip_bfloat16* Bp = Bo + ((size_t)n * 768 + w * 192 + cl) * 64 + hi * 8;

  f32x16 acc[6] = {};
#pragma unroll
  for (int ks = 0; ks < 4; ++ks) {
    u32x4 a = *(const u32x4*)(Ap + ks * 16);
#pragma unroll
    for (int t = 0; t < 6; ++t) {
      u32x4 bb = *(const u32x4*)(Bp + (size_t)(t * 32) * 64 + ks * 16);
      acc[t] = mfma32(a, bb, acc[t]);
    }
  }

  float s1[16], s2[16];
#pragma unroll
  for (int r = 0; r < 16; ++r) { s1[r] = 0.f; s2[r] = 0.f; }
#pragma unroll
  for (int t = 0; t < 6; ++t) {
#pragma unroll
    for (int r = 0; r < 16; ++r) {
      int R = (r & 3) + 8 * (r >> 2) + 4 * hi;
      int col = w * 192 + t * 32 + cl;
      float y = acc[t][r] + x[(size_t)(row0 + R) * 768 + col];
      acc[t][r] = y;
      s1[r] += y;
      s2[r] = fmaf(y, y, s2[r]);
    }
  }
#pragma unroll
  for (int r = 0; r < 16; ++r) {
#pragma unroll
    for (int off = 1; off < 32; off <<= 1) {
      s1[r] += __shfl_xor(s1[r], off);
      s2[r] += __shfl_xor(s2[r], off);
    }
  }
  if (cl == 0) {
#pragma unroll
    for (int r = 0; r < 16; ++r) {
      int R = (r & 3) + 8 * (r >> 2) + 4 * hi;
      red[w][R][0] = s1[r];
      red[w][R][1] = s2[r];
    }
  }
  __syncthreads();
  if (tid < 64) {
    int R = tid & 31, st = tid >> 5;
    redf[R][st] = red[0][R][st] + red[1][R][st] + red[2][R][st] + red[3][R][st];
  }
  __syncthreads();

  float gv[6], bv[6];
#pragma unroll
  for (int t = 0; t < 6; ++t) {
    int col = w * 192 + t * 32 + cl;
    gv[t] = gamma[n * 768 + col];
    bv[t] = beta[n * 768 + col];
  }
#pragma unroll
  for (int r = 0; r < 16; ++r) {
    int R = (r & 3) + 8 * (r >> 2) + 4 * hi;
    float mu = redf[R][0] * (1.0f / 768.0f);
    float var = redf[R][1] * (1.0f / 768.0f) - mu * mu;
    float rs = rsqrtf(var + LNEPS);
#pragma unroll
    for (int t = 0; t < 6; ++t) {
      int col = w * 192 + t * 32 + cl;
      out[(size_t)(row0 + R) * 768 + col] = (acc[t][r] - mu) * rs * gv[t] + bv[t];
    }
  }
}

// ---------------------------------------------------------------------------
extern "C" void kernel_launch(void* const* d_in, const int* in_sizes, int n_in,
                              void* d_out, int out_size, void* d_ws, size_t ws_size,
                              hipStream_t stream) {
  const float* x     = (const float*)d_in[0];
  const float* hist  = (const float*)d_in[1];
  const int*   mask  = (const int*)d_in[2];
  const float* Wq    = (const float*)d_in[3];
  const float* Wk    = (const float*)d_in[4];
  const float* Wv    = (const float*)d_in[5];
  const float* Wo    = (const float*)d_in[6];
  const float* gamma = (const float*)d_in[7];
  const float* beta  = (const float*)d_in[8];
  float* out = (float*)d_out;

  char* ws = (char*)d_ws;
  __hip_bfloat16* Qb  = (__hip_bfloat16*)ws;  ws += (size_t)NROW * II * 2;            // 3.1 MB
  __hip_bfloat16* Kb  = (__hip_bfloat16*)ws;  ws += (size_t)NDOM*BB*SS * II * 2;      // 9.4 MB
  __hip_bfloat16* Vtb = (__hip_bfloat16*)ws;  ws += (size_t)NDOM*BB*II * SS * 2;      // 9.4 MB
  __hip_bfloat16* Op  = (__hip_bfloat16*)ws;  ws += (size_t)NSPLIT * NROW * II * 2;   // 9.4 MB
  __hip_bfloat16* Ob  = (__hip_bfloat16*)ws;  ws += (size_t)NROW * II * 2;            // 3.1 MB
  float* Mp           = (float*)ws;           ws += (size_t)NSPLIT * 24 * 2 * TT * 4; // 590 KB
  float* Lp           = (float*)ws;           ws += (size_t)NSPLIT * 24 * 2 * TT * 4; // 590 KB
  __hip_bfloat16* Bkv = (__hip_bfloat16*)ws;  ws += (size_t)128 * 768 * 2;
  __hip_bfloat16* Bq  = (__hip_bfloat16*)ws;  ws += (size_t)NDOM * 64 * 768 * 2;
  __hip_bfloat16* Bo  = (__hip_bfloat16*)ws;  ws += (size_t)NDOM * 768 * 64 * 2;
  float* bias2        = (float*)ws;           ws += (size_t)BB * SS * 4;

  const int PREP_N = 128*768 + NDOM*64*768 + NDOM*768*64 + BB*SS;
  prep_kernel<<<(PREP_N + 255) / 256, 256, 0, stream>>>(mask, Wk, Wv, Wq, Wo, Bkv, Bq, Bo, bias2);
  q_gemm_kernel<<<NROW / 128, 256, 0, stream>>>(x, Bq, Qb);
  kv_gemm_kernel<<<NDOM * BB * SS / 128, 256, 0, stream>>>(hist, Bkv, Kb, Vtb);
  attn_kernel<<<48 * 32 * NSPLIT, 64, 0, stream>>>(Qb, Kb, Vtb, bias2, Op, Mp, Lp);
  combine_kernel<<<NROW * HH / 256, 256, 0, stream>>>(Op, Mp, Lp, Ob);
  oproj_ln_kernel<<<NROW / 32, 256, 0, stream>>>(x, Ob, Bo, gamma, beta, out);
}